// Round 16
// baseline (180.890 us; speedup 1.0000x reference)
//
#include <hip/hip_runtime.h>
#include <math.h>

#define B_   2
#define L1_  4096
#define L2_  6144
#define DM_  256
#define H_   8
#define DH_  32

// LDS layout (attn): 128-k staging windows, double-buffered.
// K rows padded to 80 B; V rows (128 k-span) padded to 272 B.
#define KROW 80
#define VROW 272
#define KBUF (128 * KROW)           // 10240 B per buffer
#define VBUF (32 * VROW)            //  8704 B per buffer
#define POFF (2 * KBUF + 2 * VBUF)  // 37888 B
#define LDSZ (POFF + 4 * 4096)      // 54272 B -> 3 blocks/CU (162816 <= 163840)

typedef __bf16 bf16x8 __attribute__((ext_vector_type(8)));
typedef __bf16 bf16x4 __attribute__((ext_vector_type(4)));
typedef float floatx4 __attribute__((ext_vector_type(4)));
typedef _Float16 f16;
typedef _Float16 f16x4 __attribute__((ext_vector_type(4)));
typedef _Float16 f16x8 __attribute__((ext_vector_type(8)));
typedef __fp16 fp16v2 __attribute__((ext_vector_type(2)));   // cvt_pkrtz return type

__device__ __forceinline__ bf16x8 ldb(const __bf16* p) { return *(const bf16x8*)p; }

__device__ __forceinline__ bf16x4 pack4(floatx4 v) {
    bf16x4 r;
    r[0] = (__bf16)v[0]; r[1] = (__bf16)v[1];
    r[2] = (__bf16)v[2]; r[3] = (__bf16)v[3];
    return r;
}

__device__ __forceinline__ float pkrtz(float a, float b) {
    fp16v2 p = __builtin_amdgcn_cvt_pkrtz(a, b);
    return __builtin_bit_cast(float, p);
}

// ---- convert W (qscale folded into Wq), x, source to bf16. Pure bandwidth. ----
__global__ __launch_bounds__(256) void cvt_all(
    const float* __restrict__ wq, const float* __restrict__ wk,
    const float* __restrict__ wv, const float* __restrict__ x,
    const float* __restrict__ src,
    __bf16* __restrict__ wbf, __bf16* __restrict__ xbf, __bf16* __restrict__ sbf,
    float qscale)
{
    int i = blockIdx.x * 256 + threadIdx.x;
    const float* s; __bf16* d; float sc = 1.0f; size_t off;
    if (i < 49152) {
        int seg = i >> 14;
        off = (size_t)(i & 16383) * 4;
        s = seg == 0 ? wq : (seg == 1 ? wk : wv);
        d = wbf + (size_t)seg * 65536;
        if (seg == 0) sc = qscale;
    } else if (i < 49152 + 524288) {
        off = (size_t)(i - 49152) * 4; s = x; d = xbf;
    } else {
        off = (size_t)(i - 49152 - 524288) * 4; s = src; d = sbf;
    }
    float4 v = *(const float4*)(s + off);
    bf16x4 r;
    r[0] = (__bf16)(v.x * sc); r[1] = (__bf16)(v.y * sc);
    r[2] = (__bf16)(v.z * sc); r[3] = (__bf16)(v.w * sc);
    *(bf16x4*)(d + off) = r;
}

// ---- proj: all-bf16 GEMM; Q/K out bf16, V out fp16 (transposed via LDS). ----
__global__ __launch_bounds__(256) void proj_kernel(
    const __bf16* __restrict__ xbf, const __bf16* __restrict__ sbf,
    const __bf16* __restrict__ Wbf,
    __bf16* __restrict__ qo, __bf16* __restrict__ ko, f16* __restrict__ vo)
{
    __shared__ f16 ldsV[256 * 36];   // 18 KB, V blocks only

    const int bid = blockIdx.x;
    int y, xb;
    if      (bid < 256) { y = 0; xb = bid; }
    else if (bid < 640) { y = 1; xb = bid - 256; }
    else                { y = 2; xb = bid - 640; }

    const int L = (y == 0) ? L1_ : L2_;
    const __bf16* X   = (y == 0) ? xbf : sbf;
    const __bf16* Wb  = Wbf + (size_t)y * 65536;

    const int lane = threadIdx.x & 63;
    const int w    = threadIdx.x >> 6;
    const int g    = lane >> 4;
    const int c    = lane & 15;
    const int mb   = xb * 32;
    const int b    = mb / L;
    const int lb   = mb - b * L;

    floatx4 acc[2][4];
#pragma unroll
    for (int s = 0; s < 2; s++)
#pragma unroll
        for (int n = 0; n < 4; n++) acc[s][n] = (floatx4){0.f, 0.f, 0.f, 0.f};

#pragma unroll
    for (int kc = 0; kc < 8; kc++) {
        bf16x8 xf0 = ldb(X + (size_t)(mb + c) * DM_ + kc * 32 + g * 8);
        bf16x8 xf1 = ldb(X + (size_t)(mb + 16 + c) * DM_ + kc * 32 + g * 8);
#pragma unroll
        for (int n = 0; n < 4; n++) {
            const int oc = w * 64 + n * 16 + c;
            bf16x8 wf = ldb(Wb + (size_t)oc * DM_ + kc * 32 + g * 8);
            if (y == 2) {
                acc[0][n] = __builtin_amdgcn_mfma_f32_16x16x32_bf16(xf0, wf, acc[0][n], 0, 0, 0);
                acc[1][n] = __builtin_amdgcn_mfma_f32_16x16x32_bf16(xf1, wf, acc[1][n], 0, 0, 0);
            } else {
                acc[0][n] = __builtin_amdgcn_mfma_f32_16x16x32_bf16(wf, xf0, acc[0][n], 0, 0, 0);
                acc[1][n] = __builtin_amdgcn_mfma_f32_16x16x32_bf16(wf, xf1, acc[1][n], 0, 0, 0);
            }
        }
    }

    const int bhb = b * H_;
    if (y == 2) {
        // stage [d_global][l_local] fp16 in LDS, then row-copy to VT
#pragma unroll
        for (int s = 0; s < 2; s++)
#pragma unroll
            for (int n = 0; n < 4; n++) {
                int dg = w * 64 + (n >> 1) * 32 + (n & 1) * 16 + c;
                int ll = s * 16 + g * 4;
                float2 pr;
                pr.x = pkrtz(acc[s][n][0], acc[s][n][1]);
                pr.y = pkrtz(acc[s][n][2], acc[s][n][3]);
                *(float2*)(ldsV + (size_t)dg * 36 + ll) = pr;
            }
        __syncthreads();
        const int t = threadIdx.x;
        const int h = t >> 5, d = t & 31;
        f16* row = vo + ((size_t)(bhb + h) * DH_ + d) * (size_t)L + lb;
#pragma unroll
        for (int j = 0; j < 4; j++)
            *(f16x8*)(row + j * 8) = *(const f16x8*)(ldsV + (size_t)t * 36 + j * 8);
    } else {
        __bf16* out = (y == 0) ? qo : ko;
#pragma unroll
        for (int s = 0; s < 2; s++)
#pragma unroll
            for (int n = 0; n < 4; n++) {
                int dlo = (n & 1) * 16 + g * 4;
                int h = w * 2 + (n >> 1);
                int l = lb + s * 16 + c;
                *(bf16x4*)(out + ((size_t)(bhb + h) * (size_t)L + l) * DH_ + dlo) = pack4(acc[s][n]);
            }
    }
}

// ---- flash attention v8: v7 + 128-k staging windows (half the barriers,
// ---- longer phase-drift windows for inter-block pipe overlap). Inner 64-k
// ---- tile body identical to v7 (paired P, ones-MFMA l-sum). ----
template<bool DIRECT>
__global__ __launch_bounds__(256, 2) void attn_kernel(
    const __bf16* __restrict__ Q, const __bf16* __restrict__ K,
    const f16* __restrict__ VT, float* __restrict__ out,
    f16* __restrict__ Opart, float* __restrict__ Lpart, int klen, int split)
{
    __shared__ __align__(16) unsigned char lds[LDSZ];

    const int bid  = blockIdx.x;
    const int work = (bid & 7) * (32 * split) + (bid >> 3);
    const int xb   = work & 15;
    const int bh   = (work >> 4) & 15;
    const int z    = work >> 8;

    const int lane  = threadIdx.x & 63;
    const int w     = threadIdx.x >> 6;
    const int g     = lane >> 4;
    const int c     = lane & 15;
    const int qbase = xb * 256 + w * 64;
    const int k0    = z * klen;

    bf16x8 qf[4];
#pragma unroll
    for (int h = 0; h < 4; h++)
        qf[h] = ldb(Q + ((size_t)bh * L1_ + qbase + h * 16 + c) * DH_ + g * 8);

    // staging slots: 256 threads cover 512 K-chunks (128 rows x 4) and
    // 512 V-chunks (32 rows x 16), 2 each.
    const int t0    = threadIdx.x;
    const int kArow = t0 >> 2, kAchk = t0 & 3;       // K rows 0..63
    const int kBrow = 64 + kArow;                    // K rows 64..127
    const int vArow = t0 >> 4, vAchk = t0 & 15;      // V rows 0..15
    const int vBrow = 16 + vArow;                    // V rows 16..31

    const __bf16* kgA = K  + ((size_t)bh * L2_ + kArow) * DH_ + kAchk * 8;
    const __bf16* kgB = K  + ((size_t)bh * L2_ + kBrow) * DH_ + kAchk * 8;
    const f16*    vgA = VT + ((size_t)bh * DH_ + vArow) * L2_ + vAchk * 8;
    const f16*    vgB = VT + ((size_t)bh * DH_ + vBrow) * L2_ + vAchk * 8;
    const int dKA = kArow * KROW + kAchk * 16;
    const int dKB = kBrow * KROW + kAchk * 16;
    const int dVA = 2 * KBUF + vArow * VROW + vAchk * 16;
    const int dVB = 2 * KBUF + vBrow * VROW + vAchk * 16;
    f16* Pw = (f16*)(lds + POFF + w * 4096);

    const f16x8 ones = {(f16)1.f, (f16)1.f, (f16)1.f, (f16)1.f,
                        (f16)1.f, (f16)1.f, (f16)1.f, (f16)1.f};

    floatx4 lacc[4];   // l row-sum: lane(g,c) reg r = l[q = h*16+g*4+r]
    floatx4 o[4][2];
#pragma unroll
    for (int h = 0; h < 4; h++) {
        lacc[h] = (floatx4){0.f, 0.f, 0.f, 0.f};
        o[h][0] = (floatx4){0.f, 0.f, 0.f, 0.f};
        o[h][1] = (floatx4){0.f, 0.f, 0.f, 0.f};
    }

    // prologue: stage window k0 into buffer 0
    {
        float4 ka = *(const float4*)(kgA + (size_t)k0 * DH_);
        float4 kb2 = *(const float4*)(kgB + (size_t)k0 * DH_);
        float4 va = *(const float4*)(vgA + k0);
        float4 vb2 = *(const float4*)(vgB + k0);
        *(float4*)(lds + dKA) = ka;
        *(float4*)(lds + dKB) = kb2;
        *(float4*)(lds + dVA) = va;
        *(float4*)(lds + dVB) = vb2;
    }

    int buf = 0;
#pragma unroll 1
    for (int t = 0; t < klen; t += 128) {
        __syncthreads();   // window t staged; prior reads of buf^1 done

        float4 ka, kb2, va, vb2;
        const bool more = (t + 128) < klen;
        if (more) {
            int kw = k0 + t + 128;
            ka  = *(const float4*)(kgA + (size_t)kw * DH_);
            kb2 = *(const float4*)(kgB + (size_t)kw * DH_);
            va  = *(const float4*)(vgA + kw);
            vb2 = *(const float4*)(vgB + kw);
        }

        const unsigned char* bK = lds + buf * KBUF;
        const unsigned char* bV = lds + 2 * KBUF + buf * VBUF;

#pragma unroll
        for (int u = 0; u < 2; u++) {
            bf16x8 kf[4];
#pragma unroll
            for (int st = 0; st < 4; st++)
                kf[st] = *(const bf16x8*)(bK + (u * 64 + st * 16 + c) * KROW + g * 16);
            f16x8 vf[4];
            vf[0] = *(const f16x8*)(bV + c * VROW + u * 128 + g * 16);
            vf[1] = *(const f16x8*)(bV + (16 + c) * VROW + u * 128 + g * 16);
            vf[2] = *(const f16x8*)(bV + c * VROW + u * 128 + 64 + g * 16);
            vf[3] = *(const f16x8*)(bV + (16 + c) * VROW + u * 128 + 64 + g * 16);

#pragma unroll
            for (int hp = 0; hp < 2; hp++) {
#pragma unroll
                for (int hh = 0; hh < 2; hh++) {
                    const int h = hp * 2 + hh;
                    floatx4 s[4];
#pragma unroll
                    for (int st = 0; st < 4; st++)
                        s[st] = __builtin_amdgcn_mfma_f32_16x16x32_bf16(
                                    kf[st], qf[h], (floatx4){0.f, 0.f, 0.f, 0.f}, 0, 0, 0);
#pragma unroll
                    for (int st = 0; st < 4; st++) {
                        float e0 = __builtin_amdgcn_exp2f(s[st][0]);
                        float e1 = __builtin_amdgcn_exp2f(s[st][1]);
                        float e2 = __builtin_amdgcn_exp2f(s[st][2]);
                        float e3 = __builtin_amdgcn_exp2f(s[st][3]);
                        float2 pr;
                        pr.x = pkrtz(e0, e1);
                        pr.y = pkrtz(e2, e3);
                        *(float2*)(Pw + hh * 1024 + ((st * 2 + (g >> 1)) * 16 + c) * 8 + (g & 1) * 4) = pr;
                    }
                }
                // consume both P buffers of this h-pair (wave-private, in-order DS)
#pragma unroll
                for (int kc = 0; kc < 2; kc++)
#pragma unroll
                    for (int hh = 0; hh < 2; hh++) {
                        const int h = hp * 2 + hh;
                        f16x8 pa = *(const f16x8*)(Pw + hh * 1024 + ((kc * 4 + g) * 16 + c) * 8);
                        o[h][0] = __builtin_amdgcn_mfma_f32_16x16x32_f16(pa, vf[kc * 2 + 0], o[h][0], 0, 0, 0);
                        o[h][1] = __builtin_amdgcn_mfma_f32_16x16x32_f16(pa, vf[kc * 2 + 1], o[h][1], 0, 0, 0);
                        lacc[h] = __builtin_amdgcn_mfma_f32_16x16x32_f16(pa, ones,         lacc[h], 0, 0, 0);
                    }
            }
        }

        if (more) {
            const int ob = (buf ^ 1);
            *(float4*)(lds + ob * KBUF + dKA) = ka;
            *(float4*)(lds + ob * KBUF + dKB) = kb2;
            *(float4*)(lds + ob * VBUF + dVA) = va;   // dVA already includes 2*KBUF
            *(float4*)(lds + ob * VBUF + dVB) = vb2;
        }
        buf ^= 1;
    }

    const int b  = bh / H_;
    const int hh = bh % H_;
    if (DIRECT) {
#pragma unroll
        for (int h = 0; h < 4; h++)
#pragma unroll
            for (int r = 0; r < 4; r++) {
                float inv = 1.0f / lacc[h][r];
                size_t base = ((size_t)(b * L1_ + qbase + h * 16 + g * 4 + r)) * DM_ + hh * DH_;
                out[base + c]      = o[h][0][r] * inv;
                out[base + 16 + c] = o[h][1][r] * inv;
            }
    } else {
        f16* Op = Opart + (size_t)z * ((size_t)B_ * L1_ * DM_);
#pragma unroll
        for (int h = 0; h < 4; h++) {
#pragma unroll
            for (int r = 0; r < 4; r++) {
                size_t base = ((size_t)(b * L1_ + qbase + h * 16 + g * 4 + r)) * DM_ + hh * DH_;
                Op[base + c]      = (f16)o[h][0][r];
                Op[base + 16 + c] = (f16)o[h][1][r];
            }
            if (c == 0)
#pragma unroll
                for (int r = 0; r < 4; r++)
                    Lpart[(size_t)z * ((size_t)B_ * H_ * L1_) +
                          (size_t)bh * L1_ + qbase + h * 16 + g * 4 + r] = lacc[h][r];
        }
    }
}

// out = (sum_z Opart) / (sum_z Lpart)
__global__ __launch_bounds__(256) void combine_kernel(
    const f16* __restrict__ Opart, const float* __restrict__ Lpart,
    float* __restrict__ out, int split)
{
    int t   = blockIdx.x * 256 + threadIdx.x;
    int row = t >> 6;
    int col = (t & 63) * 4;
    int b   = row >> 12;
    int q   = row & (L1_ - 1);
    int bh  = b * H_ + (col >> 5);
    float4 a = {0.f, 0.f, 0.f, 0.f};
    float ls = 0.f;
    for (int z = 0; z < split; z++) {
        const f16* Op = Opart + (size_t)z * ((size_t)B_ * L1_ * DM_);
        f16x4 v = *(const f16x4*)(Op + (size_t)row * DM_ + col);
        a.x += (float)v[0]; a.y += (float)v[1];
        a.z += (float)v[2]; a.w += (float)v[3];
        ls += Lpart[(size_t)z * ((size_t)B_ * H_ * L1_) + (size_t)bh * L1_ + q];
    }
    float inv = 1.0f / ls;
    float4 r; r.x = a.x * inv; r.y = a.y * inv; r.z = a.z * inv; r.w = a.w * inv;
    *(float4*)(out + (size_t)row * DM_ + col) = r;
}

extern "C" void kernel_launch(void* const* d_in, const int* in_sizes, int n_in,
                              void* d_out, int out_size, void* d_ws, size_t ws_size,
                              hipStream_t stream) {
    const float* x   = (const float*)d_in[0];
    const float* src = (const float*)d_in[1];
    const float* Wq  = (const float*)d_in[2];
    const float* Wk  = (const float*)d_in[3];
    const float* Wv  = (const float*)d_in[4];
    float* out = (float*)d_out;

    const float qscale = 1.4426950408889634f / sqrtf((float)DH_); // log2e * Dh^-0.5

    const size_t nW = 3 * 65536;
    const size_t nQ = (size_t)B_ * H_ * L1_ * DH_;   // 2,097,152
    const size_t nK = (size_t)B_ * H_ * L2_ * DH_;   // 3,145,728
    const size_t nX = nQ;

    // persistent: [W | Q | K | VT], union region: phase1 xbf/sbf, phase2 Opart/Lpart
    __bf16* wbf = (__bf16*)d_ws;
    __bf16* qws = wbf + nW;
    __bf16* kws = qws + nQ;
    f16*    vt  = (f16*)(kws + nK);
    size_t unionOff = ((nW + nQ + 2 * nK) * 2 + 255) & ~(size_t)255;
    __bf16* xbf = (__bf16*)((char*)d_ws + unionOff);
    __bf16* sbf = xbf + nX;

    const size_t oPartB = (size_t)B_ * L1_ * DM_ * sizeof(f16);   // 4 MB / split
    const size_t lPartB = (size_t)B_ * H_ * L1_ * 4;              // 256 KB / split
    const size_t avail  = ws_size > unionOff ? ws_size - unionOff : 0;
    int split = 1;
    if      (avail >= 8 * (oPartB + lPartB)) split = 8;
    else if (avail >= 6 * (oPartB + lPartB)) split = 6;
    else if (avail >= 4 * (oPartB + lPartB)) split = 4;
    else if (avail >= 2 * (oPartB + lPartB)) split = 2;
    f16*   Opart = (f16*)((char*)d_ws + unionOff);
    float* Lpart = (float*)((char*)d_ws + unionOff + (size_t)split * oPartB);

    cvt_all<<<dim3(5312), 256, 0, stream>>>(Wq, Wk, Wv, x, src, wbf, xbf, sbf, qscale);
    proj_kernel<<<dim3(1024), 256, 0, stream>>>(xbf, sbf, wbf, qws, kws, vt);

    if (split > 1) {
        attn_kernel<false><<<dim3(256 * split), 256, 0, stream>>>(
            qws, kws, vt, nullptr, Opart, Lpart, L2_ / split, split);
        combine_kernel<<<dim3(2048), 256, 0, stream>>>(Opart, Lpart, out, split);
    } else {
        attn_kernel<true><<<dim3(256), 256, 0, stream>>>(
            qws, kws, vt, out, nullptr, nullptr, L2_, 1);
    }
}

// Round 17
// 177.249 us; speedup vs baseline: 1.0205x; 1.0205x over previous
//
#include <hip/hip_runtime.h>
#include <math.h>

#define B_   2
#define L1_  4096
#define L2_  6144
#define DM_  256
#define H_   8
#define DH_  32

// LDS layout (attn): K dbuf rows padded to 80 B, V dbuf rows padded to 144 B.
#define KROW 80
#define VROW 144
#define KBUF (64 * KROW)            // 5120 B
#define VBUF (32 * VROW)            // 4608 B
#define POFF (2 * KBUF + 2 * VBUF)  // 19456 B
#define LDSZ (POFF + 4 * 4096)      // 35840 B

typedef __bf16 bf16x8 __attribute__((ext_vector_type(8)));
typedef __bf16 bf16x4 __attribute__((ext_vector_type(4)));
typedef float floatx4 __attribute__((ext_vector_type(4)));
typedef _Float16 f16;
typedef _Float16 f16x4 __attribute__((ext_vector_type(4)));
typedef _Float16 f16x8 __attribute__((ext_vector_type(8)));
typedef __fp16 fp16v2 __attribute__((ext_vector_type(2)));   // cvt_pkrtz return type

__device__ __forceinline__ bf16x8 ldb(const __bf16* p) { return *(const bf16x8*)p; }

__device__ __forceinline__ bf16x4 pack4(floatx4 v) {
    bf16x4 r;
    r[0] = (__bf16)v[0]; r[1] = (__bf16)v[1];
    r[2] = (__bf16)v[2]; r[3] = (__bf16)v[3];
    return r;
}

__device__ __forceinline__ float pkrtz(float a, float b) {
    fp16v2 p = __builtin_amdgcn_cvt_pkrtz(a, b);
    return __builtin_bit_cast(float, p);
}

// ---- convert W (qscale folded into Wq), x, source to bf16. Pure bandwidth. ----
__global__ __launch_bounds__(256) void cvt_all(
    const float* __restrict__ wq, const float* __restrict__ wk,
    const float* __restrict__ wv, const float* __restrict__ x,
    const float* __restrict__ src,
    __bf16* __restrict__ wbf, __bf16* __restrict__ xbf, __bf16* __restrict__ sbf,
    float qscale)
{
    int i = blockIdx.x * 256 + threadIdx.x;
    const float* s; __bf16* d; float sc = 1.0f; size_t off;
    if (i < 49152) {
        int seg = i >> 14;
        off = (size_t)(i & 16383) * 4;
        s = seg == 0 ? wq : (seg == 1 ? wk : wv);
        d = wbf + (size_t)seg * 65536;
        if (seg == 0) sc = qscale;
    } else if (i < 49152 + 524288) {
        off = (size_t)(i - 49152) * 4; s = x; d = xbf;
    } else {
        off = (size_t)(i - 49152 - 524288) * 4; s = src; d = sbf;
    }
    float4 v = *(const float4*)(s + off);
    bf16x4 r;
    r[0] = (__bf16)(v.x * sc); r[1] = (__bf16)(v.y * sc);
    r[2] = (__bf16)(v.z * sc); r[3] = (__bf16)(v.w * sc);
    *(bf16x4*)(d + off) = r;
}

// ---- proj: all-bf16 GEMM; Q/K out bf16, V out fp16 (transposed via LDS). ----
__global__ __launch_bounds__(256) void proj_kernel(
    const __bf16* __restrict__ xbf, const __bf16* __restrict__ sbf,
    const __bf16* __restrict__ Wbf,
    __bf16* __restrict__ qo, __bf16* __restrict__ ko, f16* __restrict__ vo)
{
    __shared__ f16 ldsV[256 * 36];   // 18 KB, V blocks only

    const int bid = blockIdx.x;
    int y, xb;
    if      (bid < 256) { y = 0; xb = bid; }
    else if (bid < 640) { y = 1; xb = bid - 256; }
    else                { y = 2; xb = bid - 640; }

    const int L = (y == 0) ? L1_ : L2_;
    const __bf16* X   = (y == 0) ? xbf : sbf;
    const __bf16* Wb  = Wbf + (size_t)y * 65536;

    const int lane = threadIdx.x & 63;
    const int w    = threadIdx.x >> 6;
    const int g    = lane >> 4;
    const int c    = lane & 15;
    const int mb   = xb * 32;
    const int b    = mb / L;
    const int lb   = mb - b * L;

    floatx4 acc[2][4];
#pragma unroll
    for (int s = 0; s < 2; s++)
#pragma unroll
        for (int n = 0; n < 4; n++) acc[s][n] = (floatx4){0.f, 0.f, 0.f, 0.f};

#pragma unroll
    for (int kc = 0; kc < 8; kc++) {
        bf16x8 xf0 = ldb(X + (size_t)(mb + c) * DM_ + kc * 32 + g * 8);
        bf16x8 xf1 = ldb(X + (size_t)(mb + 16 + c) * DM_ + kc * 32 + g * 8);
#pragma unroll
        for (int n = 0; n < 4; n++) {
            const int oc = w * 64 + n * 16 + c;
            bf16x8 wf = ldb(Wb + (size_t)oc * DM_ + kc * 32 + g * 8);
            if (y == 2) {
                acc[0][n] = __builtin_amdgcn_mfma_f32_16x16x32_bf16(xf0, wf, acc[0][n], 0, 0, 0);
                acc[1][n] = __builtin_amdgcn_mfma_f32_16x16x32_bf16(xf1, wf, acc[1][n], 0, 0, 0);
            } else {
                acc[0][n] = __builtin_amdgcn_mfma_f32_16x16x32_bf16(wf, xf0, acc[0][n], 0, 0, 0);
                acc[1][n] = __builtin_amdgcn_mfma_f32_16x16x32_bf16(wf, xf1, acc[1][n], 0, 0, 0);
            }
        }
    }

    const int bhb = b * H_;
    if (y == 2) {
        // stage [d_global][l_local] fp16 in LDS, then row-copy to VT
#pragma unroll
        for (int s = 0; s < 2; s++)
#pragma unroll
            for (int n = 0; n < 4; n++) {
                int dg = w * 64 + (n >> 1) * 32 + (n & 1) * 16 + c;
                int ll = s * 16 + g * 4;
                float2 pr;
                pr.x = pkrtz(acc[s][n][0], acc[s][n][1]);
                pr.y = pkrtz(acc[s][n][2], acc[s][n][3]);
                *(float2*)(ldsV + (size_t)dg * 36 + ll) = pr;
            }
        __syncthreads();
        const int t = threadIdx.x;
        const int h = t >> 5, d = t & 31;
        f16* row = vo + ((size_t)(bhb + h) * DH_ + d) * (size_t)L + lb;
#pragma unroll
        for (int j = 0; j < 4; j++)
            *(f16x8*)(row + j * 8) = *(const f16x8*)(ldsV + (size_t)t * 36 + j * 8);
    } else {
        __bf16* out = (y == 0) ? qo : ko;
#pragma unroll
        for (int s = 0; s < 2; s++)
#pragma unroll
            for (int n = 0; n < 4; n++) {
                int dlo = (n & 1) * 16 + g * 4;
                int h = w * 2 + (n >> 1);
                int l = lb + s * 16 + c;
                *(bf16x4*)(out + ((size_t)(bhb + h) * (size_t)L + l) * DH_ + dlo) = pack4(acc[s][n]);
            }
    }
}

// ---- flash attention v7: LDS-staged K/V (64-k dbuf) + l-row-sum via ones-MFMA.
template<bool DIRECT>
__global__ __launch_bounds__(256, 2) void attn_kernel(
    const __bf16* __restrict__ Q, const __bf16* __restrict__ K,
    const f16* __restrict__ VT, float* __restrict__ out,
    f16* __restrict__ Opart, float* __restrict__ Lpart, int klen, int split)
{
    __shared__ __align__(16) unsigned char lds[LDSZ];

    const int bid  = blockIdx.x;
    const int work = (bid & 7) * (32 * split) + (bid >> 3);
    const int xb   = work & 15;
    const int bh   = (work >> 4) & 15;
    const int z    = work >> 8;

    const int lane  = threadIdx.x & 63;
    const int w     = threadIdx.x >> 6;
    const int g     = lane >> 4;
    const int c     = lane & 15;
    const int qbase = xb * 256 + w * 64;
    const int k0    = z * klen;

    bf16x8 qf[4];
#pragma unroll
    for (int h = 0; h < 4; h++)
        qf[h] = ldb(Q + ((size_t)bh * L1_ + qbase + h * 16 + c) * DH_ + g * 8);

    const int krow = w * 16 + (lane >> 2);
    const int kchk = lane & 3;
    const int vrow = w * 8 + (lane >> 3);
    const int vchk = lane & 7;
    const __bf16* kgbase = K  + ((size_t)bh * L2_ + krow) * DH_ + kchk * 8;
    const f16*    vgbase = VT + ((size_t)bh * DH_ + vrow) * L2_ + vchk * 8;
    unsigned char* dstK = lds + krow * KROW + kchk * 16;
    unsigned char* dstV = lds + 2 * KBUF + vrow * VROW + vchk * 16;
    f16* Pw = (f16*)(lds + POFF + w * 4096);

    const f16x8 ones = {(f16)1.f, (f16)1.f, (f16)1.f, (f16)1.f,
                        (f16)1.f, (f16)1.f, (f16)1.f, (f16)1.f};

    floatx4 lacc[4];   // l row-sum accumulator: lane(g,c) reg r = l[q = h*16+g*4+r]
    floatx4 o[4][2];
#pragma unroll
    for (int h = 0; h < 4; h++) {
        lacc[h] = (floatx4){0.f, 0.f, 0.f, 0.f};
        o[h][0] = (floatx4){0.f, 0.f, 0.f, 0.f};
        o[h][1] = (floatx4){0.f, 0.f, 0.f, 0.f};
    }

    // prologue: stage tile k0 into buffer 0
    {
        float4 kr = *(const float4*)(kgbase + (size_t)k0 * DH_);
        float4 vr = *(const float4*)(vgbase + k0);
        *(float4*)dstK = kr;
        *(float4*)dstV = vr;
    }

    int buf = 0;
#pragma unroll 1
    for (int t = 0; t < klen; t += 64) {
        __syncthreads();   // tile t staged; previous iter's reads of buf^1 done

        float4 kr, vr;
        const bool more = (t + 64) < klen;
        if (more) {
            kr = *(const float4*)(kgbase + (size_t)(k0 + t + 64) * DH_);
            vr = *(const float4*)(vgbase + (k0 + t + 64));
        }

        const unsigned char* bK = lds + buf * KBUF;
        const unsigned char* bV = lds + 2 * KBUF + buf * VBUF;
        bf16x8 kf[4];
#pragma unroll
        for (int st = 0; st < 4; st++)
            kf[st] = *(const bf16x8*)(bK + (st * 16 + c) * KROW + g * 16);
        f16x8 vf[4];
        vf[0] = *(const f16x8*)(bV + c * VROW + g * 16);
        vf[1] = *(const f16x8*)(bV + (16 + c) * VROW + g * 16);
        vf[2] = *(const f16x8*)(bV + c * VROW + 64 + g * 16);
        vf[3] = *(const f16x8*)(bV + (16 + c) * VROW + 64 + g * 16);

#pragma unroll
        for (int hp = 0; hp < 2; hp++) {
#pragma unroll
            for (int hh = 0; hh < 2; hh++) {
                const int h = hp * 2 + hh;
                floatx4 s[4];
#pragma unroll
                for (int st = 0; st < 4; st++)
                    s[st] = __builtin_amdgcn_mfma_f32_16x16x32_bf16(
                                kf[st], qf[h], (floatx4){0.f, 0.f, 0.f, 0.f}, 0, 0, 0);
#pragma unroll
                for (int st = 0; st < 4; st++) {
                    float e0 = __builtin_amdgcn_exp2f(s[st][0]);
                    float e1 = __builtin_amdgcn_exp2f(s[st][1]);
                    float e2 = __builtin_amdgcn_exp2f(s[st][2]);
                    float e3 = __builtin_amdgcn_exp2f(s[st][3]);
                    float2 pr;
                    pr.x = pkrtz(e0, e1);
                    pr.y = pkrtz(e2, e3);
                    *(float2*)(Pw + hh * 1024 + ((st * 2 + (g >> 1)) * 16 + c) * 8 + (g & 1) * 4) = pr;
                }
            }
            // consume both P buffers of this h-pair (wave-private: in-order DS)
#pragma unroll
            for (int kc = 0; kc < 2; kc++)
#pragma unroll
                for (int hh = 0; hh < 2; hh++) {
                    const int h = hp * 2 + hh;
                    f16x8 pa = *(const f16x8*)(Pw + hh * 1024 + ((kc * 4 + g) * 16 + c) * 8);
                    o[h][0] = __builtin_amdgcn_mfma_f32_16x16x32_f16(pa, vf[kc * 2 + 0], o[h][0], 0, 0, 0);
                    o[h][1] = __builtin_amdgcn_mfma_f32_16x16x32_f16(pa, vf[kc * 2 + 1], o[h][1], 0, 0, 0);
                    lacc[h] = __builtin_amdgcn_mfma_f32_16x16x32_f16(pa, ones,         lacc[h], 0, 0, 0);
                }
        }

        if (more) {
            *(float4*)(lds + (buf ^ 1) * KBUF + krow * KROW + kchk * 16) = kr;
            *(float4*)(lds + 2 * KBUF + (buf ^ 1) * VBUF + vrow * VROW + vchk * 16) = vr;
        }
        buf ^= 1;
    }

    const int b  = bh / H_;
    const int hh = bh % H_;
    if (DIRECT) {
#pragma unroll
        for (int h = 0; h < 4; h++)
#pragma unroll
            for (int r = 0; r < 4; r++) {
                float inv = 1.0f / lacc[h][r];
                size_t base = ((size_t)(b * L1_ + qbase + h * 16 + g * 4 + r)) * DM_ + hh * DH_;
                out[base + c]      = o[h][0][r] * inv;
                out[base + 16 + c] = o[h][1][r] * inv;
            }
    } else {
        f16* Op = Opart + (size_t)z * ((size_t)B_ * L1_ * DM_);
#pragma unroll
        for (int h = 0; h < 4; h++) {
#pragma unroll
            for (int r = 0; r < 4; r++) {
                size_t base = ((size_t)(b * L1_ + qbase + h * 16 + g * 4 + r)) * DM_ + hh * DH_;
                Op[base + c]      = (f16)o[h][0][r];
                Op[base + 16 + c] = (f16)o[h][1][r];
            }
            if (c == 0)   // l[q=g*4+r] lives in lacc[h][r] of every c; lane c==0 stores
#pragma unroll
                for (int r = 0; r < 4; r++)
                    Lpart[(size_t)z * ((size_t)B_ * H_ * L1_) +
                          (size_t)bh * L1_ + qbase + h * 16 + g * 4 + r] = lacc[h][r];
        }
    }
}

// out = (sum_z Opart) / (sum_z Lpart)
__global__ __launch_bounds__(256) void combine_kernel(
    const f16* __restrict__ Opart, const float* __restrict__ Lpart,
    float* __restrict__ out, int split)
{
    int t   = blockIdx.x * 256 + threadIdx.x;
    int row = t >> 6;
    int col = (t & 63) * 4;
    int b   = row >> 12;
    int q   = row & (L1_ - 1);
    int bh  = b * H_ + (col >> 5);
    float4 a = {0.f, 0.f, 0.f, 0.f};
    float ls = 0.f;
    for (int z = 0; z < split; z++) {
        const f16* Op = Opart + (size_t)z * ((size_t)B_ * L1_ * DM_);
        f16x4 v = *(const f16x4*)(Op + (size_t)row * DM_ + col);
        a.x += (float)v[0]; a.y += (float)v[1];
        a.z += (float)v[2]; a.w += (float)v[3];
        ls += Lpart[(size_t)z * ((size_t)B_ * H_ * L1_) + (size_t)bh * L1_ + q];
    }
    float inv = 1.0f / ls;
    float4 r; r.x = a.x * inv; r.y = a.y * inv; r.z = a.z * inv; r.w = a.w * inv;
    *(float4*)(out + (size_t)row * DM_ + col) = r;
}

extern "C" void kernel_launch(void* const* d_in, const int* in_sizes, int n_in,
                              void* d_out, int out_size, void* d_ws, size_t ws_size,
                              hipStream_t stream) {
    const float* x   = (const float*)d_in[0];
    const float* src = (const float*)d_in[1];
    const float* Wq  = (const float*)d_in[2];
    const float* Wk  = (const float*)d_in[3];
    const float* Wv  = (const float*)d_in[4];
    float* out = (float*)d_out;

    const float qscale = 1.4426950408889634f / sqrtf((float)DH_); // log2e * Dh^-0.5

    const size_t nW = 3 * 65536;
    const size_t nQ = (size_t)B_ * H_ * L1_ * DH_;   // 2,097,152
    const size_t nK = (size_t)B_ * H_ * L2_ * DH_;   // 3,145,728
    const size_t nX = nQ;

    // persistent: [W | Q | K | VT], union region: phase1 xbf/sbf, phase2 Opart/Lpart
    __bf16* wbf = (__bf16*)d_ws;
    __bf16* qws = wbf + nW;
    __bf16* kws = qws + nQ;
    f16*    vt  = (f16*)(kws + nK);
    size_t unionOff = ((nW + nQ + 2 * nK) * 2 + 255) & ~(size_t)255;
    __bf16* xbf = (__bf16*)((char*)d_ws + unionOff);
    __bf16* sbf = xbf + nX;

    const size_t oPartB = (size_t)B_ * L1_ * DM_ * sizeof(f16);   // 4 MB / split
    const size_t lPartB = (size_t)B_ * H_ * L1_ * 4;              // 256 KB / split
    const size_t avail  = ws_size > unionOff ? ws_size - unionOff : 0;
    int split = 1;
    if      (avail >= 8 * (oPartB + lPartB)) split = 8;
    else if (avail >= 6 * (oPartB + lPartB)) split = 6;
    else if (avail >= 4 * (oPartB + lPartB)) split = 4;
    else if (avail >= 2 * (oPartB + lPartB)) split = 2;
    f16*   Opart = (f16*)((char*)d_ws + unionOff);
    float* Lpart = (float*)((char*)d_ws + unionOff + (size_t)split * oPartB);

    cvt_all<<<dim3(5312), 256, 0, stream>>>(Wq, Wk, Wv, x, src, wbf, xbf, sbf, qscale);
    proj_kernel<<<dim3(1024), 256, 0, stream>>>(xbf, sbf, wbf, qws, kws, vt);

    if (split > 1) {
        attn_kernel<false><<<dim3(256 * split), 256, 0, stream>>>(
            qws, kws, vt, nullptr, Opart, Lpart, L2_ / split, split);
        combine_kernel<<<dim3(2048), 256, 0, stream>>>(Opart, Lpart, out, split);
    } else {
        attn_kernel<true><<<dim3(256), 256, 0, stream>>>(
            qws, kws, vt, out, nullptr, nullptr, L2_, 1);
    }
}